// Round 7
// baseline (315.779 us; speedup 1.0000x reference)
//
#include <hip/hip_runtime.h>

// ---------------------------------------------------------------------------
// SelfAttention: B=4, S=2048, D=1024, fp32 in/out, causal, no 1/sqrt(d).
// fp16 MFMA (16x16x32), fp32 accumulate, fp32 softmax.
//
// R15 = R14 resubmitted verbatim (R6 bench was an infra failure: "MI355X
// container failed twice" — no kernel signal; audit found no OOB/hang).
//
//  - QKV: R10's qkv192 (measured 63.4 us, best of 5 QKV schedules).
//  - softmax split: rowstat computes per-row {max, 1/sum} (bitwise-
//    identical reductions), 64 KB overlaying the dead Q slab; pv_fused
//    stages the A-operand straight from S fp32, applying
//    p=(k<=q)?exp(s-m)*inv:0 in registers and ds_writing fp16 into the
//    XOR layout the fragment reads undo. P bitwise identical to the old
//    softmax's -> output bitwise identical. Deletes P write (18 MB),
//    P read, and one dispatch.
//
// ws layout (MiB):
//   [0,32)    Q,K fp16 slabs; MS row-stats (64 KB) overlays after scores
//   [32,48)   Vt fp16 (b,e,s) — written by QKV epilogue
//   [48,112)  S fp32 (4x2048x2048)
//   [48,64)   x_h fp16      (over S; dead before S written)
//   [64,70)   Wh  fp16 [3072,1024] (over S; dead before S written)
// ---------------------------------------------------------------------------

typedef _Float16 h8 __attribute__((ext_vector_type(8)));
typedef _Float16 h4 __attribute__((ext_vector_type(4)));
typedef float f32x4 __attribute__((ext_vector_type(4)));

#define BM 128
#define BN 128

__device__ __forceinline__ void gl_lds16(const _Float16* g, _Float16* l) {
    __builtin_amdgcn_global_load_lds(
        (const __attribute__((address_space(1))) void*)g,
        (__attribute__((address_space(3))) void*)l, 16, 0, 0);
}

#define BARX do { asm volatile("" ::: "memory"); __builtin_amdgcn_s_barrier(); \
                  asm volatile("" ::: "memory"); } while (0)
#define VMW(n) asm volatile("s_waitcnt vmcnt(" #n ")" ::: "memory")

// ---------------------------------------------------------------------------
// qkv192 (R10 verbatim): A = x_h [8192][1024], B = Wh [3072][1024].
// 8 waves 2Mx4N, per-wave 128x48 (8 M-frags x 3 N-frags), acc[8][3].
// LDS: Ab0@0 Ab1@16384 Ab2@32768 ([256][64]); Bb0@49152 Bb1@61440
// ([192][64]) = 144 KiB. Dense 128B-line staging, XOR seg swizzle on the
// global source. 4 phases/window, vmcnt(4) once per window.
// ---------------------------------------------------------------------------

#define SA_LO(gp, ab) do { gl_lds16((gp),          (ab) + wv * 1024); \
                           gl_lds16((gp) + 8192,   (ab) + wv * 1024 + 512); } while (0)
#define SA_HI(gp, ab) do { gl_lds16((gp) + 131072, (ab) + wv * 1024 + 8192); \
                           gl_lds16((gp) + 139264, (ab) + wv * 1024 + 8704); } while (0)
#define SB_LO(gp, bb) do { gl_lds16((gp),          (bb) + wv * 1024); \
                           gl_lds16((gp) + 8192,   (bb) + wv * 1024 + 512); } while (0)
#define SB_HI(gp2, bb)     gl_lds16((gp2),         (bb) + 8192 + wv * 512)

#define LDA(ab, h, ap) do { _Pragma("unroll") \
    for (int i = 0; i < 4; i++) \
        af[i] = *(const h8*)&(ab)[abase + (h) * 4096 + i * 1024 + (ap)]; } while (0)
#define LDB(bb, ap) do { _Pragma("unroll") \
    for (int j = 0; j < 3; j++) \
        bf[j] = *(const h8*)&(bb)[bbase + j * 1024 + (ap)]; } while (0)

#define MMP(h) do { __builtin_amdgcn_s_setprio(1); _Pragma("unroll") \
    for (int i = 0; i < 4; i++) { _Pragma("unroll") \
        for (int j = 0; j < 3; j++) \
            acc[(h) * 4 + i][j] = __builtin_amdgcn_mfma_f32_16x16x32_f16( \
                af[i], bf[j], acc[(h) * 4 + i][j], 0, 0, 0); } \
    __builtin_amdgcn_s_setprio(0); } while (0)

__global__ __launch_bounds__(512, 2) void qkv192(
    const _Float16* __restrict__ A, const _Float16* __restrict__ B,
    _Float16* __restrict__ C)
{
    __shared__ __align__(16) _Float16 sm[73728];   // 144 KiB

    // XCD-bijective swizzle (512 % 8 == 0)
    const int bid = blockIdx.x;
    const int wg = (bid & 7) * 64 + (bid >> 3);
    const int by = wg >> 4, bx = wg & 15;
    const int m0 = by * 256, n0 = bx * 192;

    const int tid = threadIdx.x;
    const int l = tid & 63;
    const int wv = tid >> 6;

    // staging addressing: lane l -> row +(l>>3), global seg (l&7)^((l>>3)&7)
    const int prow = wv * 16 + (l >> 3);
    const int pseg = ((l & 7) ^ ((l >> 3) & 7)) * 8;
    const _Float16* gA  = A + (size_t)(m0 + prow) * 1024 + pseg;
    const _Float16* gB  = B + (size_t)(n0 + prow) * 1024 + pseg;
    const _Float16* gB2 = B + (size_t)(n0 + 128 + wv * 8 + (l >> 3)) * 1024 + pseg;

    // fragment addressing
    const int la = l & 15, qd = l >> 4;
    const int wmr = (wv >> 2) * 128;            // 2 M row-groups
    const int wnr = (wv & 3) * 48;              // 4 N col-groups of 48
    const int ap0 = ((qd) ^ (la & 7)) * 8;      // k-step s=0 phys seg
    const int ap1 = ((4 + qd) ^ (la & 7)) * 8;  // k-step s=1 phys seg
    const int abase = (wmr + la) * 64;
    const int bbase = (wnr + la) * 64;

    _Float16* a0 = sm;
    _Float16* a1 = sm + 16384;
    _Float16* a2 = sm + 32768;
    _Float16* b0 = sm + 49152;
    _Float16* b1 = sm + 61440;

    f32x4 acc[8][3];
    #pragma unroll
    for (int i = 0; i < 8; i++)
        #pragma unroll
        for (int j = 0; j < 3; j++)
            acc[i][j] = (f32x4){0.f, 0.f, 0.f, 0.f};

    // prologue: A(0)->Ab0, B(0)->Bb0, A(1)->Ab1 (11 ops); force A(0)+B(0)
    SA_LO(gA, a0);      SA_HI(gA, a0);
    SB_LO(gB, b0);      SB_HI(gB2, b0);
    SA_LO(gA + 64, a1); SA_HI(gA + 64, a1);
    VMW(4);
    BARX;

    const _Float16* pA  = gA + 128;    // k-offset of A(2)
    const _Float16* pB  = gB + 64;     // k-offset of B(1)
    const _Float16* pB2 = gB2 + 64;

    #pragma unroll 1
    for (int n = 0; n < 14; ++n) {
        h8 af[4], bf[3];
        LDB(b0, ap0); LDA(a0, 0, ap0); SB_LO(pB, b1);  BARX; MMP(0); BARX;
        LDA(a0, 1, ap0);               SB_HI(pB2, b1); BARX; MMP(1); BARX;
        LDB(b0, ap1); LDA(a0, 0, ap1); SA_LO(pA, a2);  BARX; MMP(0); BARX;
        LDA(a0, 1, ap1);               SA_HI(pA, a2);  BARX; MMP(1); VMW(4); BARX;
        _Float16* t = a0; a0 = a1; a1 = a2; a2 = t;
        t = b0; b0 = b1; b1 = t;
        pA += 64; pB += 64; pB2 += 64;
    }
    {   // W14: stage only B(15); drain everything at end
        h8 af[4], bf[3];
        LDB(b0, ap0); LDA(a0, 0, ap0); SB_LO(pB, b1);  BARX; MMP(0); BARX;
        LDA(a0, 1, ap0);               SB_HI(pB2, b1); BARX; MMP(1); BARX;
        LDB(b0, ap1); LDA(a0, 0, ap1);                 BARX; MMP(0); BARX;
        LDA(a0, 1, ap1);                               BARX; MMP(1); VMW(0); BARX;
        _Float16* t = a0; a0 = a1; a1 = a2; a2 = t;
        t = b0; b0 = b1; b1 = t;
    }
    {   // W15: reads only
        h8 af[4], bf[3];
        LDB(b0, ap0); LDA(a0, 0, ap0); BARX; MMP(0); BARX;
        LDA(a0, 1, ap0);               BARX; MMP(1); BARX;
        LDB(b0, ap1); LDA(a0, 0, ap1); BARX; MMP(0); BARX;
        LDA(a0, 1, ap1);               BARX; MMP(1);
    }

    // epilogue: D layout col=la, row=qd*4+rr. Slab per 16-aligned column.
    #pragma unroll
    for (int i = 0; i < 8; i++) {
        const int m = m0 + wmr + i * 16 + qd * 4;
        #pragma unroll
        for (int j = 0; j < 3; j++) {
            const int col16 = n0 + wnr + j * 16;
            const int slab = col16 >> 10;
            if (slab < 2) {
                const size_t base = (size_t)slab * 8388608 + (col16 & 1023) + la;
                #pragma unroll
                for (int rr = 0; rr < 4; rr++)
                    C[base + (size_t)(m + rr) * 1024] = (_Float16)acc[i][j][rr];
            } else {
                _Float16* Vt = C + (size_t)2 * 8388608;
                const int e = col16 + la - 2048;
                const int b = m >> 11;
                const int sl = m & 2047;
                h4 vv = { (_Float16)acc[i][j][0], (_Float16)acc[i][j][1],
                          (_Float16)acc[i][j][2], (_Float16)acc[i][j][3] };
                *(h4*)(Vt + (size_t)b * 2097152 + (size_t)e * 2048 + sl) = vv;
            }
        }
    }
}

// ---------------------------------------------------------------------------
// NT GEMM (R8 structure) kept for scores (SWZ=2).
// ---------------------------------------------------------------------------
template<int SWZ, int OM, bool KLIM>
__global__ __launch_bounds__(256) void gemm_nt(
    const _Float16* __restrict__ A, const _Float16* __restrict__ B,
    void* __restrict__ Cp, int N, int K,
    size_t sAz, size_t sBz, size_t sCz)
{
    __shared__ __align__(16) char smem[32768];
    _Float16* As = (_Float16*)smem;              // 2 x 4096 halves (k-stages)
    _Float16* Bs = (_Float16*)(smem + 16384);    // 2 x 4096 halves

    int bx, by;
    if (SWZ == 1) {
        const int r = blockIdx.x & 7, q2 = blockIdx.x >> 3;
        bx = q2 >> 3;
        by = ((q2 & 7) << 3) | r;
    } else if (SWZ == 2) {
        const int r = blockIdx.x & 7, g = blockIdx.x >> 3;   // g in 0..16
        if (g <= r) { by = r;      bx = g; }
        else        { by = 15 - r; bx = g - (r + 1); }
    } else {                                      // SWZ == 3
        const int r = blockIdx.x & 7, g = blockIdx.x >> 3;   // g in 0..15
        by = (g & 1) ? (15 - r) : r;
        bx = g >> 1;
    }

    const int tid  = threadIdx.x;
    const int lane = tid & 63;
    const int wv   = tid >> 6;
    const int m0 = by * BM, n0 = bx * BN;
    const size_t z = blockIdx.z;

    const int lr = lane >> 2;
    const int lc = ((lane & 3) ^ ((lane >> 3) & 3)) * 8;
    const _Float16* pA0 = A + z * sAz + (size_t)(m0 + wv * 16 + lr) * K + lc;
    const _Float16* pA1 = pA0 + (size_t)64 * K;
    const _Float16* pB0 = B + z * sBz + (size_t)(n0 + wv * 16 + lr) * K + lc;
    const _Float16* pB1 = pB0 + (size_t)64 * K;
    _Float16* lA0 = As + wv * 512;
    _Float16* lA1 = As + (wv + 4) * 512;
    _Float16* lB0 = Bs + wv * 512;
    _Float16* lB1 = Bs + (wv + 4) * 512;

    const int la = lane & 15;
    const int qd = lane >> 4;
    const int wm = (wv >> 1) * 64;
    const int wn = (wv & 1) * 64;
    const int sg = (qd ^ ((la >> 1) & 3)) * 8;

    f32x4 acc[4][4];
    #pragma unroll
    for (int i = 0; i < 4; i++)
        #pragma unroll
        for (int j = 0; j < 4; j++)
            acc[i][j] = (f32x4){0.f, 0.f, 0.f, 0.f};

    const int kEnd = KLIM ? (m0 + BM) : K;

    for (int k0 = 0; k0 < kEnd; k0 += 64) {
        gl_lds16(pA0,      lA0);
        gl_lds16(pA1,      lA1);
        gl_lds16(pB0,      lB0);
        gl_lds16(pB1,      lB1);
        gl_lds16(pA0 + 32, lA0 + 4096);
        gl_lds16(pA1 + 32, lA1 + 4096);
        gl_lds16(pB0 + 32, lB0 + 4096);
        gl_lds16(pB1 + 32, lB1 + 4096);
        pA0 += 64; pA1 += 64; pB0 += 64; pB1 += 64;
        __syncthreads();

        #pragma unroll
        for (int s = 0; s < 2; s++) {
            h8 af[4], bf[4];
            #pragma unroll
            for (int i = 0; i < 4; i++)
                af[i] = *(const h8*)&As[s * 4096 + (wm + i * 16 + la) * 32 + sg];
            #pragma unroll
            for (int i = 0; i < 4; i++)
                bf[i] = *(const h8*)&Bs[s * 4096 + (wn + i * 16 + la) * 32 + sg];
            #pragma unroll
            for (int i = 0; i < 4; i++)
                #pragma unroll
                for (int j = 0; j < 4; j++)
                    acc[i][j] = __builtin_amdgcn_mfma_f32_16x16x32_f16(af[i], bf[j], acc[i][j], 0, 0, 0);
        }
        __syncthreads();
    }

    if (OM == 2) {
        _Float16* C = (_Float16*)Cp;
        if (n0 < 2048) {
            #pragma unroll
            for (int i = 0; i < 4; i++)
                #pragma unroll
                for (int j = 0; j < 4; j++) {
                    const int col  = n0 + wn + j * 16 + la;
                    const size_t base = (size_t)(col >> 10) * 8388608 + (col & 1023);
                    #pragma unroll
                    for (int rr = 0; rr < 4; rr++)
                        C[base + (size_t)(m0 + wm + i * 16 + qd * 4 + rr) * 1024] =
                            (_Float16)acc[i][j][rr];
                }
        } else {
            _Float16* Vt = C + (size_t)2 * 8388608;
            #pragma unroll
            for (int i = 0; i < 4; i++) {
                const int m  = m0 + wm + i * 16 + qd * 4;
                const int b  = m >> 11;
                const int sl = m & 2047;
                _Float16* Vb = Vt + (size_t)b * 2097152 + sl;
                #pragma unroll
                for (int j = 0; j < 4; j++) {
                    const int e = n0 - 2048 + wn + j * 16 + la;
                    h4 vv = { (_Float16)acc[i][j][0], (_Float16)acc[i][j][1],
                              (_Float16)acc[i][j][2], (_Float16)acc[i][j][3] };
                    *(h4*)(Vb + (size_t)e * 2048) = vv;
                }
            }
        }
    } else {
        float* C = (float*)Cp + z * sCz;
        #pragma unroll
        for (int i = 0; i < 4; i++)
            #pragma unroll
            for (int j = 0; j < 4; j++)
                #pragma unroll
                for (int rr = 0; rr < 4; rr++)
                    C[(size_t)(m0 + wm + i * 16 + qd * 4 + rr) * N + (n0 + wn + j * 16 + la)] =
                        acc[i][j][rr];
    }
}

// ---------------------------------------------------------------------------
// pv_fused: out = softmax(S) @ Vt^T with softmax applied during A-staging.
// Same 128^2 NT structure as gemm_nt<3,0,true>; A staged from S fp32:
// p = (k<=q) ? __expf(s - m_row) * inv_row : 0  (bitwise identical to the
// old softmax kernel's P). Thread t stages row t&127, k-substage t>>7
// (32 cols); writes 4 x ds_write_b128 with the XOR layout the fragment
// reads undo (8-row write pattern covers all 32 banks -> conflict-free).
// ---------------------------------------------------------------------------
__global__ __launch_bounds__(256) void pv_fused(
    const float* __restrict__ S, const float2* __restrict__ MS,
    const _Float16* __restrict__ V, float* __restrict__ C)
{
    __shared__ __align__(16) char smem[32768];
    _Float16* As = (_Float16*)smem;              // 2 stages x [128][32]
    _Float16* Bs = (_Float16*)(smem + 16384);

    // SWZ=3 residue decode (grid.x = 128)
    const int r = blockIdx.x & 7, g = blockIdx.x >> 3;   // g in 0..15
    const int by = (g & 1) ? (15 - r) : r;
    const int bx = g >> 1;
    const int m0 = by * BM, n0 = bx * BN;
    const size_t z = blockIdx.z;

    const int tid  = threadIdx.x;
    const int lane = tid & 63;
    const int wv   = tid >> 6;

    // A staging (reg->LDS with softmax): row t&127, stage t>>7
    const int arow = tid & 127;
    const int astg = tid >> 7;
    const float* Srow = S + z * 4194304 + (size_t)(m0 + arow) * 2048 + astg * 32;
    const float2 ms = MS[z * 2048 + m0 + arow];
    const int qrow = m0 + arow;
    const int ax = (arow >> 1) & 3;                      // phys-group XOR
    _Float16* Arow = As + astg * 4096 + arow * 32;

    // B (Vt) staging via gl_lds, K = 2048
    const int lr = lane >> 2;
    const int lc = ((lane & 3) ^ ((lane >> 3) & 3)) * 8;
    const _Float16* pB0 = V + z * 2097152 + (size_t)(n0 + wv * 16 + lr) * 2048 + lc;
    const _Float16* pB1 = pB0 + (size_t)64 * 2048;
    _Float16* lB0 = Bs + wv * 512;
    _Float16* lB1 = Bs + (wv + 4) * 512;

    // fragments
    const int la = lane & 15;
    const int qd = lane >> 4;
    const int wm = (wv >> 1) * 64;
    const int wn = (wv & 1) * 64;
    const int sg = (qd ^ ((la >> 1) & 3)) * 8;

    f32x4 acc[4][4];
    #pragma unroll
    for (int i = 0; i < 4; i++)
        #pragma unroll
        for (int j = 0; j < 4; j++)
            acc[i][j] = (f32x4){0.f, 0.f, 0.f, 0.f};

    const int kEnd = m0 + BM;

    #pragma unroll 1
    for (int k0 = 0; k0 < kEnd; k0 += 64) {
        // B stage (async)
        gl_lds16(pB0,      lB0);
        gl_lds16(pB1,      lB1);
        gl_lds16(pB0 + 32, lB0 + 4096);
        gl_lds16(pB1 + 32, lB1 + 4096);
        pB0 += 64; pB1 += 64;

        // A stage: 32 cols [k0+astg*32, +32) of S -> masked exp -> fp16 LDS
        #pragma unroll
        for (int gg = 0; gg < 4; gg++) {
            const float4 a4 = *(const float4*)(Srow + k0 + gg * 8);
            const float4 b4 = *(const float4*)(Srow + k0 + gg * 8 + 4);
            const int kb = k0 + astg * 32 + gg * 8;
            h8 pk;
            pk[0] = (_Float16)((kb + 0 <= qrow) ? __expf(a4.x - ms.x) * ms.y : 0.f);
            pk[1] = (_Float16)((kb + 1 <= qrow) ? __expf(a4.y - ms.x) * ms.y : 0.f);
            pk[2] = (_Float16)((kb + 2 <= qrow) ? __expf(a4.z - ms.x) * ms.y : 0.f);
            pk[3] = (_Float16)((kb + 3 <= qrow) ? __expf(a4.w - ms.x) * ms.y : 0.f);
            pk[4] = (_Float16)((kb + 4 <= qrow) ? __expf(b4.x - ms.x) * ms.y : 0.f);
            pk[5] = (_Float16)((kb + 5 <= qrow) ? __expf(b4.y - ms.x) * ms.y : 0.f);
            pk[6] = (_Float16)((kb + 6 <= qrow) ? __expf(b4.z - ms.x) * ms.y : 0.f);
            pk[7] = (_Float16)((kb + 7 <= qrow) ? __expf(b4.w - ms.x) * ms.y : 0.f);
            *(h8*)(Arow + ((gg ^ ax) * 8)) = pk;
        }
        __syncthreads();

        #pragma unroll
        for (int s = 0; s < 2; s++) {
            h8 af[4], bf[4];
            #pragma unroll
            for (int i = 0; i < 4; i++)
                af[i] = *(const h8*)&As[s * 4096 + (wm + i * 16 + la) * 32 + sg];
            #pragma unroll
            for (int i = 0; i < 4; i++)
                bf[i] = *(const h8*)&Bs[s * 4096 + (wn + i * 16 + la) * 32 + sg];
            #pragma unroll
            for (int i = 0; i < 4; i++)
                #pragma unroll
                for (int j = 0; j < 4; j++)
                    acc[i][j] = __builtin_amdgcn_mfma_f32_16x16x32_f16(af[i], bf[j], acc[i][j], 0, 0, 0);
        }
        __syncthreads();
    }

    float* Cz = C + z * 2097152;
    #pragma unroll
    for (int i = 0; i < 4; i++)
        #pragma unroll
        for (int j = 0; j < 4; j++)
            #pragma unroll
            for (int rr = 0; rr < 4; rr++)
                Cz[(size_t)(m0 + wm + i * 16 + qd * 4 + rr) * 1024 + (n0 + wn + j * 16 + la)] =
                    acc[i][j][rr];
}

// fused fp32->fp16: blocks [0,4096) convert x (8M), [4096,5632) convert W (3x1M)
__global__ __launch_bounds__(256) void cvt_all(
    const float* __restrict__ x, const float* __restrict__ Wq,
    const float* __restrict__ Wk, const float* __restrict__ Wv,
    _Float16* __restrict__ x_h, _Float16* __restrict__ Wh)
{
    const int bid = blockIdx.x;
    const float* src; _Float16* dst; size_t off;
    if (bid < 4096) {
        src = x; dst = x_h; off = (size_t)bid * 2048;
    } else {
        const int b2 = bid - 4096;
        const int w = b2 >> 9;
        src = (w == 0) ? Wq : ((w == 1) ? Wk : Wv);
        dst = Wh + (size_t)w * 1048576;
        off = (size_t)(b2 & 511) * 2048;
    }
    const size_t i = off + (size_t)threadIdx.x * 8;
    float4 a = *(const float4*)(src + i);
    float4 b = *(const float4*)(src + i + 4);
    h8 o = { (_Float16)a.x, (_Float16)a.y, (_Float16)a.z, (_Float16)a.w,
             (_Float16)b.x, (_Float16)b.y, (_Float16)b.z, (_Float16)b.w };
    *(h8*)(dst + i) = o;
}

// causal row stats: per row compute {max, 1/sum} (reduction order bitwise
// identical to the old softmax kernel). Thread t owns cols 8t..8t+7.
__global__ __launch_bounds__(256) void rowstat(const float* __restrict__ S,
                                               float2* __restrict__ MS)
{
    const int idx = blockIdx.x;          // 0..8191
    const int q = idx & 2047;
    const float* Srow = S + (size_t)idx * 2048;
    const int t = threadIdx.x;
    const int k0 = t * 8;
    const int lane = t & 63, wv = t >> 6;
    __shared__ float red[4];

    float v[8];
    const bool any = (k0 <= q);
    if (any) {
        float4 a = *(const float4*)(Srow + k0);
        float4 b = *(const float4*)(Srow + k0 + 4);
        v[0] = a.x; v[1] = a.y; v[2] = a.z; v[3] = a.w;
        v[4] = b.x; v[5] = b.y; v[6] = b.z; v[7] = b.w;
    }
    float mx = -3.4e38f;
    #pragma unroll
    for (int j = 0; j < 8; j++)
        if (any && k0 + j <= q) mx = fmaxf(mx, v[j]);
    #pragma unroll
    for (int o = 32; o > 0; o >>= 1) mx = fmaxf(mx, __shfl_down(mx, o, 64));
    if (lane == 0) red[wv] = mx;
    __syncthreads();
    const float mall = fmaxf(fmaxf(red[0], red[1]), fmaxf(red[2], red[3]));
    __syncthreads();

    float sum = 0.f;
    #pragma unroll
    for (int j = 0; j < 8; j++) {
        float e = (any && k0 + j <= q) ? __expf(v[j] - mall) : 0.f;
        sum += e;
    }
    #pragma unroll
    for (int o = 32; o > 0; o >>= 1) sum += __shfl_down(sum, o, 64);
    if (lane == 0) red[wv] = sum;
    __syncthreads();
    if (t == 0) {
        const float inv = 1.f / (red[0] + red[1] + red[2] + red[3]);
        MS[idx] = make_float2(mall, inv);
    }
}

extern "C" void kernel_launch(void* const* d_in, const int* in_sizes, int n_in,
                              void* d_out, int out_size, void* d_ws, size_t ws_size,
                              hipStream_t stream) {
    const float* x  = (const float*)d_in[0];
    const float* Wq = (const float*)d_in[1];
    const float* Wk = (const float*)d_in[2];
    const float* Wv = (const float*)d_in[3];
    float* out = (float*)d_out;

    const size_t MiB = 1024 * 1024;
    char* ws = (char*)d_ws;
    _Float16* QKVh = (_Float16*)ws;                     // Q,K slabs + Vt at slab 2
    _Float16* Vt   = QKVh + (size_t)2 * 8388608;        // [32,48) MiB, (b,e,s)
    float*    S    = (float*)(ws + 48 * MiB);           // 64 MiB
    _Float16* x_h  = (_Float16*)(ws + 48 * MiB);        // 16 MiB (over S)
    _Float16* Wh   = (_Float16*)(ws + 64 * MiB);        // 6 MiB  (over S)
    float2*   MS   = (float2*)ws;                       // 64 KB (over dead Q)

    const dim3 blk(256);

    // 0) fp32 -> fp16 conversions (one dispatch)
    cvt_all<<<dim3(5632), blk, 0, stream>>>(x, Wq, Wk, Wv, x_h, Wh);

    // 1) QKV fused, 256x192 dense-staged pipeline (R10 best): M=8192, N=3072
    qkv192<<<dim3(512), dim3(512), 0, stream>>>(x_h, Wh, QKVh);

    // 2) scores: balanced lower-triangle decode, 136 tiles/batch
    gemm_nt<2, 0, false><<<dim3(136, 1, 4), blk, 0, stream>>>(
        QKVh, QKVh + 8388608, S, 2048, 1024,
        (size_t)2097152, (size_t)2097152, (size_t)4194304);

    // 3) causal row stats {max, 1/sum} (Q,K slabs dead -> MS overlays)
    rowstat<<<dim3(4 * 2048), blk, 0, stream>>>(S, MS);

    // 4) out = softmax(S) @ Vt^T fused, K clipped at m0+128
    pv_fused<<<dim3(128, 1, 4), blk, 0, stream>>>(S, MS, Vt, out);
}

// Round 8
// 276.525 us; speedup vs baseline: 1.1420x; 1.1420x over previous
//
#include <hip/hip_runtime.h>

// ---------------------------------------------------------------------------
// SelfAttention: B=4, S=2048, D=1024, fp32 in/out, causal, no 1/sqrt(d).
// fp16 MFMA (16x16x32), fp32 accumulate, fp32 softmax.
//
// R16 = R15 with pv_fused software-pipelined. R15's pv_fused was
// latency-bound (MfmaUtil 5.3%, VALUBusy 14.5%, Occ 12.6% — S loads used
// immediately, ~500-900cy exposed per K-step, 2 blocks/CU). Fix: prefetch
// next iteration's 32 S-floats into registers before the exp/LDS/MFMA
// phases of the current one (~800cy of cover), + fast path for fully
// unmasked 8-groups. P values bitwise identical (same __expf(s-m)*inv,
// same mask) -> output bitwise identical.
//
// ws layout (MiB):
//   [0,32)    Q,K fp16 slabs; MS row-stats (64 KB) overlays after scores
//   [32,48)   Vt fp16 (b,e,s) — written by QKV epilogue
//   [48,112)  S fp32 (4x2048x2048)
//   [48,64)   x_h fp16      (over S; dead before S written)
//   [64,70)   Wh  fp16 [3072,1024] (over S; dead before S written)
// ---------------------------------------------------------------------------

typedef _Float16 h8 __attribute__((ext_vector_type(8)));
typedef _Float16 h4 __attribute__((ext_vector_type(4)));
typedef float f32x4 __attribute__((ext_vector_type(4)));

#define BM 128
#define BN 128

__device__ __forceinline__ void gl_lds16(const _Float16* g, _Float16* l) {
    __builtin_amdgcn_global_load_lds(
        (const __attribute__((address_space(1))) void*)g,
        (__attribute__((address_space(3))) void*)l, 16, 0, 0);
}

#define BARX do { asm volatile("" ::: "memory"); __builtin_amdgcn_s_barrier(); \
                  asm volatile("" ::: "memory"); } while (0)
#define VMW(n) asm volatile("s_waitcnt vmcnt(" #n ")" ::: "memory")

// ---------------------------------------------------------------------------
// qkv192 (R10 verbatim): A = x_h [8192][1024], B = Wh [3072][1024].
// 8 waves 2Mx4N, per-wave 128x48 (8 M-frags x 3 N-frags), acc[8][3].
// LDS: Ab0@0 Ab1@16384 Ab2@32768 ([256][64]); Bb0@49152 Bb1@61440
// ([192][64]) = 144 KiB. Dense 128B-line staging, XOR seg swizzle on the
// global source. 4 phases/window, vmcnt(4) once per window.
// ---------------------------------------------------------------------------

#define SA_LO(gp, ab) do { gl_lds16((gp),          (ab) + wv * 1024); \
                           gl_lds16((gp) + 8192,   (ab) + wv * 1024 + 512); } while (0)
#define SA_HI(gp, ab) do { gl_lds16((gp) + 131072, (ab) + wv * 1024 + 8192); \
                           gl_lds16((gp) + 139264, (ab) + wv * 1024 + 8704); } while (0)
#define SB_LO(gp, bb) do { gl_lds16((gp),          (bb) + wv * 1024); \
                           gl_lds16((gp) + 8192,   (bb) + wv * 1024 + 512); } while (0)
#define SB_HI(gp2, bb)     gl_lds16((gp2),         (bb) + 8192 + wv * 512)

#define LDA(ab, h, ap) do { _Pragma("unroll") \
    for (int i = 0; i < 4; i++) \
        af[i] = *(const h8*)&(ab)[abase + (h) * 4096 + i * 1024 + (ap)]; } while (0)
#define LDB(bb, ap) do { _Pragma("unroll") \
    for (int j = 0; j < 3; j++) \
        bf[j] = *(const h8*)&(bb)[bbase + j * 1024 + (ap)]; } while (0)

#define MMP(h) do { __builtin_amdgcn_s_setprio(1); _Pragma("unroll") \
    for (int i = 0; i < 4; i++) { _Pragma("unroll") \
        for (int j = 0; j < 3; j++) \
            acc[(h) * 4 + i][j] = __builtin_amdgcn_mfma_f32_16x16x32_f16( \
                af[i], bf[j], acc[(h) * 4 + i][j], 0, 0, 0); } \
    __builtin_amdgcn_s_setprio(0); } while (0)

__global__ __launch_bounds__(512, 2) void qkv192(
    const _Float16* __restrict__ A, const _Float16* __restrict__ B,
    _Float16* __restrict__ C)
{
    __shared__ __align__(16) _Float16 sm[73728];   // 144 KiB

    // XCD-bijective swizzle (512 % 8 == 0)
    const int bid = blockIdx.x;
    const int wg = (bid & 7) * 64 + (bid >> 3);
    const int by = wg >> 4, bx = wg & 15;
    const int m0 = by * 256, n0 = bx * 192;

    const int tid = threadIdx.x;
    const int l = tid & 63;
    const int wv = tid >> 6;

    // staging addressing: lane l -> row +(l>>3), global seg (l&7)^((l>>3)&7)
    const int prow = wv * 16 + (l >> 3);
    const int pseg = ((l & 7) ^ ((l >> 3) & 7)) * 8;
    const _Float16* gA  = A + (size_t)(m0 + prow) * 1024 + pseg;
    const _Float16* gB  = B + (size_t)(n0 + prow) * 1024 + pseg;
    const _Float16* gB2 = B + (size_t)(n0 + 128 + wv * 8 + (l >> 3)) * 1024 + pseg;

    // fragment addressing
    const int la = l & 15, qd = l >> 4;
    const int wmr = (wv >> 2) * 128;            // 2 M row-groups
    const int wnr = (wv & 3) * 48;              // 4 N col-groups of 48
    const int ap0 = ((qd) ^ (la & 7)) * 8;      // k-step s=0 phys seg
    const int ap1 = ((4 + qd) ^ (la & 7)) * 8;  // k-step s=1 phys seg
    const int abase = (wmr + la) * 64;
    const int bbase = (wnr + la) * 64;

    _Float16* a0 = sm;
    _Float16* a1 = sm + 16384;
    _Float16* a2 = sm + 32768;
    _Float16* b0 = sm + 49152;
    _Float16* b1 = sm + 61440;

    f32x4 acc[8][3];
    #pragma unroll
    for (int i = 0; i < 8; i++)
        #pragma unroll
        for (int j = 0; j < 3; j++)
            acc[i][j] = (f32x4){0.f, 0.f, 0.f, 0.f};

    // prologue: A(0)->Ab0, B(0)->Bb0, A(1)->Ab1 (11 ops); force A(0)+B(0)
    SA_LO(gA, a0);      SA_HI(gA, a0);
    SB_LO(gB, b0);      SB_HI(gB2, b0);
    SA_LO(gA + 64, a1); SA_HI(gA + 64, a1);
    VMW(4);
    BARX;

    const _Float16* pA  = gA + 128;    // k-offset of A(2)
    const _Float16* pB  = gB + 64;     // k-offset of B(1)
    const _Float16* pB2 = gB2 + 64;

    #pragma unroll 1
    for (int n = 0; n < 14; ++n) {
        h8 af[4], bf[3];
        LDB(b0, ap0); LDA(a0, 0, ap0); SB_LO(pB, b1);  BARX; MMP(0); BARX;
        LDA(a0, 1, ap0);               SB_HI(pB2, b1); BARX; MMP(1); BARX;
        LDB(b0, ap1); LDA(a0, 0, ap1); SA_LO(pA, a2);  BARX; MMP(0); BARX;
        LDA(a0, 1, ap1);               SA_HI(pA, a2);  BARX; MMP(1); VMW(4); BARX;
        _Float16* t = a0; a0 = a1; a1 = a2; a2 = t;
        t = b0; b0 = b1; b1 = t;
        pA += 64; pB += 64; pB2 += 64;
    }
    {   // W14: stage only B(15); drain everything at end
        h8 af[4], bf[3];
        LDB(b0, ap0); LDA(a0, 0, ap0); SB_LO(pB, b1);  BARX; MMP(0); BARX;
        LDA(a0, 1, ap0);               SB_HI(pB2, b1); BARX; MMP(1); BARX;
        LDB(b0, ap1); LDA(a0, 0, ap1);                 BARX; MMP(0); BARX;
        LDA(a0, 1, ap1);                               BARX; MMP(1); VMW(0); BARX;
        _Float16* t = a0; a0 = a1; a1 = a2; a2 = t;
        t = b0; b0 = b1; b1 = t;
    }
    {   // W15: reads only
        h8 af[4], bf[3];
        LDB(b0, ap0); LDA(a0, 0, ap0); BARX; MMP(0); BARX;
        LDA(a0, 1, ap0);               BARX; MMP(1); BARX;
        LDB(b0, ap1); LDA(a0, 0, ap1); BARX; MMP(0); BARX;
        LDA(a0, 1, ap1);               BARX; MMP(1);
    }

    // epilogue: D layout col=la, row=qd*4+rr. Slab per 16-aligned column.
    #pragma unroll
    for (int i = 0; i < 8; i++) {
        const int m = m0 + wmr + i * 16 + qd * 4;
        #pragma unroll
        for (int j = 0; j < 3; j++) {
            const int col16 = n0 + wnr + j * 16;
            const int slab = col16 >> 10;
            if (slab < 2) {
                const size_t base = (size_t)slab * 8388608 + (col16 & 1023) + la;
                #pragma unroll
                for (int rr = 0; rr < 4; rr++)
                    C[base + (size_t)(m + rr) * 1024] = (_Float16)acc[i][j][rr];
            } else {
                _Float16* Vt = C + (size_t)2 * 8388608;
                const int e = col16 + la - 2048;
                const int b = m >> 11;
                const int sl = m & 2047;
                h4 vv = { (_Float16)acc[i][j][0], (_Float16)acc[i][j][1],
                          (_Float16)acc[i][j][2], (_Float16)acc[i][j][3] };
                *(h4*)(Vt + (size_t)b * 2097152 + (size_t)e * 2048 + sl) = vv;
            }
        }
    }
}

// ---------------------------------------------------------------------------
// NT GEMM (R8 structure) kept for scores (SWZ=2).
// ---------------------------------------------------------------------------
template<int SWZ, int OM, bool KLIM>
__global__ __launch_bounds__(256) void gemm_nt(
    const _Float16* __restrict__ A, const _Float16* __restrict__ B,
    void* __restrict__ Cp, int N, int K,
    size_t sAz, size_t sBz, size_t sCz)
{
    __shared__ __align__(16) char smem[32768];
    _Float16* As = (_Float16*)smem;              // 2 x 4096 halves (k-stages)
    _Float16* Bs = (_Float16*)(smem + 16384);    // 2 x 4096 halves

    int bx, by;
    if (SWZ == 1) {
        const int r = blockIdx.x & 7, q2 = blockIdx.x >> 3;
        bx = q2 >> 3;
        by = ((q2 & 7) << 3) | r;
    } else if (SWZ == 2) {
        const int r = blockIdx.x & 7, g = blockIdx.x >> 3;   // g in 0..16
        if (g <= r) { by = r;      bx = g; }
        else        { by = 15 - r; bx = g - (r + 1); }
    } else {                                      // SWZ == 3
        const int r = blockIdx.x & 7, g = blockIdx.x >> 3;   // g in 0..15
        by = (g & 1) ? (15 - r) : r;
        bx = g >> 1;
    }

    const int tid  = threadIdx.x;
    const int lane = tid & 63;
    const int wv   = tid >> 6;
    const int m0 = by * BM, n0 = bx * BN;
    const size_t z = blockIdx.z;

    const int lr = lane >> 2;
    const int lc = ((lane & 3) ^ ((lane >> 3) & 3)) * 8;
    const _Float16* pA0 = A + z * sAz + (size_t)(m0 + wv * 16 + lr) * K + lc;
    const _Float16* pA1 = pA0 + (size_t)64 * K;
    const _Float16* pB0 = B + z * sBz + (size_t)(n0 + wv * 16 + lr) * K + lc;
    const _Float16* pB1 = pB0 + (size_t)64 * K;
    _Float16* lA0 = As + wv * 512;
    _Float16* lA1 = As + (wv + 4) * 512;
    _Float16* lB0 = Bs + wv * 512;
    _Float16* lB1 = Bs + (wv + 4) * 512;

    const int la = lane & 15;
    const int qd = lane >> 4;
    const int wm = (wv >> 1) * 64;
    const int wn = (wv & 1) * 64;
    const int sg = (qd ^ ((la >> 1) & 3)) * 8;

    f32x4 acc[4][4];
    #pragma unroll
    for (int i = 0; i < 4; i++)
        #pragma unroll
        for (int j = 0; j < 4; j++)
            acc[i][j] = (f32x4){0.f, 0.f, 0.f, 0.f};

    const int kEnd = KLIM ? (m0 + BM) : K;

    for (int k0 = 0; k0 < kEnd; k0 += 64) {
        gl_lds16(pA0,      lA0);
        gl_lds16(pA1,      lA1);
        gl_lds16(pB0,      lB0);
        gl_lds16(pB1,      lB1);
        gl_lds16(pA0 + 32, lA0 + 4096);
        gl_lds16(pA1 + 32, lA1 + 4096);
        gl_lds16(pB0 + 32, lB0 + 4096);
        gl_lds16(pB1 + 32, lB1 + 4096);
        pA0 += 64; pA1 += 64; pB0 += 64; pB1 += 64;
        __syncthreads();

        #pragma unroll
        for (int s = 0; s < 2; s++) {
            h8 af[4], bf[4];
            #pragma unroll
            for (int i = 0; i < 4; i++)
                af[i] = *(const h8*)&As[s * 4096 + (wm + i * 16 + la) * 32 + sg];
            #pragma unroll
            for (int i = 0; i < 4; i++)
                bf[i] = *(const h8*)&Bs[s * 4096 + (wn + i * 16 + la) * 32 + sg];
            #pragma unroll
            for (int i = 0; i < 4; i++)
                #pragma unroll
                for (int j = 0; j < 4; j++)
                    acc[i][j] = __builtin_amdgcn_mfma_f32_16x16x32_f16(af[i], bf[j], acc[i][j], 0, 0, 0);
        }
        __syncthreads();
    }

    if (OM == 2) {
        _Float16* C = (_Float16*)Cp;
        if (n0 < 2048) {
            #pragma unroll
            for (int i = 0; i < 4; i++)
                #pragma unroll
                for (int j = 0; j < 4; j++) {
                    const int col  = n0 + wn + j * 16 + la;
                    const size_t base = (size_t)(col >> 10) * 8388608 + (col & 1023);
                    #pragma unroll
                    for (int rr = 0; rr < 4; rr++)
                        C[base + (size_t)(m0 + wm + i * 16 + qd * 4 + rr) * 1024] =
                            (_Float16)acc[i][j][rr];
                }
        } else {
            _Float16* Vt = C + (size_t)2 * 8388608;
            #pragma unroll
            for (int i = 0; i < 4; i++) {
                const int m  = m0 + wm + i * 16 + qd * 4;
                const int b  = m >> 11;
                const int sl = m & 2047;
                _Float16* Vb = Vt + (size_t)b * 2097152 + sl;
                #pragma unroll
                for (int j = 0; j < 4; j++) {
                    const int e = n0 - 2048 + wn + j * 16 + la;
                    h4 vv = { (_Float16)acc[i][j][0], (_Float16)acc[i][j][1],
                              (_Float16)acc[i][j][2], (_Float16)acc[i][j][3] };
                    *(h4*)(Vb + (size_t)e * 2048) = vv;
                }
            }
        }
    } else {
        float* C = (float*)Cp + z * sCz;
        #pragma unroll
        for (int i = 0; i < 4; i++)
            #pragma unroll
            for (int j = 0; j < 4; j++)
                #pragma unroll
                for (int rr = 0; rr < 4; rr++)
                    C[(size_t)(m0 + wm + i * 16 + qd * 4 + rr) * N + (n0 + wn + j * 16 + la)] =
                        acc[i][j][rr];
    }
}

// ---------------------------------------------------------------------------
// pv_fused (pipelined): out = softmax(S) @ Vt^T, softmax applied during
// A-staging. Next iteration's S-block is prefetched into registers before
// the current exp/LDS/MFMA phases (~800cy of latency cover). P values
// bitwise identical to the old softmax kernel's.
// ---------------------------------------------------------------------------
__global__ __launch_bounds__(256) void pv_fused(
    const float* __restrict__ S, const float2* __restrict__ MS,
    const _Float16* __restrict__ V, float* __restrict__ C)
{
    __shared__ __align__(16) char smem[32768];
    _Float16* As = (_Float16*)smem;              // 2 stages x [128][32]
    _Float16* Bs = (_Float16*)(smem + 16384);

    // SWZ=3 residue decode (grid.x = 128)
    const int r = blockIdx.x & 7, g = blockIdx.x >> 3;   // g in 0..15
    const int by = (g & 1) ? (15 - r) : r;
    const int bx = g >> 1;
    const int m0 = by * BM, n0 = bx * BN;
    const size_t z = blockIdx.z;

    const int tid  = threadIdx.x;
    const int lane = tid & 63;
    const int wv   = tid >> 6;

    // A staging (reg->LDS with softmax): row t&127, stage t>>7
    const int arow = tid & 127;
    const int astg = tid >> 7;
    const float* Srow = S + z * 4194304 + (size_t)(m0 + arow) * 2048 + astg * 32;
    const float2 ms = MS[z * 2048 + m0 + arow];
    const int qrow = m0 + arow;
    const int ax = (arow >> 1) & 3;                      // phys-group XOR
    _Float16* Arow = As + astg * 4096 + arow * 32;

    // B (Vt) staging via gl_lds, K = 2048
    const int lr = lane >> 2;
    const int lc = ((lane & 3) ^ ((lane >> 3) & 3)) * 8;
    const _Float16* pB0 = V + z * 2097152 + (size_t)(n0 + wv * 16 + lr) * 2048 + lc;
    const _Float16* pB1 = pB0 + (size_t)64 * 2048;
    _Float16* lB0 = Bs + wv * 512;
    _Float16* lB1 = Bs + (wv + 4) * 512;

    // fragments
    const int la = lane & 15;
    const int qd = lane >> 4;
    const int wm = (wv >> 1) * 64;
    const int wn = (wv & 1) * 64;
    const int sg = (qd ^ ((la >> 1) & 3)) * 8;

    f32x4 acc[4][4];
    #pragma unroll
    for (int i = 0; i < 4; i++)
        #pragma unroll
        for (int j = 0; j < 4; j++)
            acc[i][j] = (f32x4){0.f, 0.f, 0.f, 0.f};

    const int kEnd = m0 + BM;

    // prefetch iter-0 S into registers
    float4 pa[4], pb[4];
    #pragma unroll
    for (int gg = 0; gg < 4; gg++) {
        pa[gg] = *(const float4*)(Srow + gg * 8);
        pb[gg] = *(const float4*)(Srow + gg * 8 + 4);
    }

    #pragma unroll 1
    for (int k0 = 0; k0 < kEnd; k0 += 64) {
        // B stage (async, lands at the barrier's vmcnt drain)
        gl_lds16(pB0,      lB0);
        gl_lds16(pB1,      lB1);
        gl_lds16(pB0 + 32, lB0 + 4096);
        gl_lds16(pB1 + 32, lB1 + 4096);
        pB0 += 64; pB1 += 64;

        // issue next-iteration S loads early (hidden under exp+MFMA)
        const int kn = (k0 + 64 < kEnd) ? (k0 + 64) : k0;   // in-bounds clamp
        float4 na[4], nb[4];
        #pragma unroll
        for (int gg = 0; gg < 4; gg++) {
            na[gg] = *(const float4*)(Srow + kn + gg * 8);
            nb[gg] = *(const float4*)(Srow + kn + gg * 8 + 4);
        }

        // softmax-apply current regs -> fp16 -> LDS (XOR layout)
        #pragma unroll
        for (int gg = 0; gg < 4; gg++) {
            const int kb = k0 + astg * 32 + gg * 8;
            h8 pk;
            if (kb + 7 <= qrow) {                 // fully unmasked fast path
                pk[0] = (_Float16)(__expf(pa[gg].x - ms.x) * ms.y);
                pk[1] = (_Float16)(__expf(pa[gg].y - ms.x) * ms.y);
                pk[2] = (_Float16)(__expf(pa[gg].z - ms.x) * ms.y);
                pk[3] = (_Float16)(__expf(pa[gg].w - ms.x) * ms.y);
                pk[4] = (_Float16)(__expf(pb[gg].x - ms.x) * ms.y);
                pk[5] = (_Float16)(__expf(pb[gg].y - ms.x) * ms.y);
                pk[6] = (_Float16)(__expf(pb[gg].z - ms.x) * ms.y);
                pk[7] = (_Float16)(__expf(pb[gg].w - ms.x) * ms.y);
            } else {
                pk[0] = (_Float16)((kb + 0 <= qrow) ? __expf(pa[gg].x - ms.x) * ms.y : 0.f);
                pk[1] = (_Float16)((kb + 1 <= qrow) ? __expf(pa[gg].y - ms.x) * ms.y : 0.f);
                pk[2] = (_Float16)((kb + 2 <= qrow) ? __expf(pa[gg].z - ms.x) * ms.y : 0.f);
                pk[3] = (_Float16)((kb + 3 <= qrow) ? __expf(pa[gg].w - ms.x) * ms.y : 0.f);
                pk[4] = (_Float16)((kb + 4 <= qrow) ? __expf(pb[gg].x - ms.x) * ms.y : 0.f);
                pk[5] = (_Float16)((kb + 5 <= qrow) ? __expf(pb[gg].y - ms.x) * ms.y : 0.f);
                pk[6] = (_Float16)((kb + 6 <= qrow) ? __expf(pb[gg].z - ms.x) * ms.y : 0.f);
                pk[7] = (_Float16)((kb + 7 <= qrow) ? __expf(pb[gg].w - ms.x) * ms.y : 0.f);
            }
            *(h8*)(Arow + ((gg ^ ax) * 8)) = pk;
        }
        __syncthreads();

        #pragma unroll
        for (int s = 0; s < 2; s++) {
            h8 af[4], bf[4];
            #pragma unroll
            for (int i = 0; i < 4; i++)
                af[i] = *(const h8*)&As[s * 4096 + (wm + i * 16 + la) * 32 + sg];
            #pragma unroll
            for (int i = 0; i < 4; i++)
                bf[i] = *(const h8*)&Bs[s * 4096 + (wn + i * 16 + la) * 32 + sg];
            #pragma unroll
            for (int i = 0; i < 4; i++)
                #pragma unroll
                for (int j = 0; j < 4; j++)
                    acc[i][j] = __builtin_amdgcn_mfma_f32_16x16x32_f16(af[i], bf[j], acc[i][j], 0, 0, 0);
        }
        __syncthreads();

        #pragma unroll
        for (int gg = 0; gg < 4; gg++) { pa[gg] = na[gg]; pb[gg] = nb[gg]; }
    }

    float* Cz = C + z * 2097152;
    #pragma unroll
    for (int i = 0; i < 4; i++)
        #pragma unroll
        for (int j = 0; j < 4; j++)
            #pragma unroll
            for (int rr = 0; rr < 4; rr++)
                Cz[(size_t)(m0 + wm + i * 16 + qd * 4 + rr) * 1024 + (n0 + wn + j * 16 + la)] =
                    acc[i][j][rr];
}

// fused fp32->fp16: blocks [0,4096) convert x (8M), [4096,5632) convert W (3x1M)
__global__ __launch_bounds__(256) void cvt_all(
    const float* __restrict__ x, const float* __restrict__ Wq,
    const float* __restrict__ Wk, const float* __restrict__ Wv,
    _Float16* __restrict__ x_h, _Float16* __restrict__ Wh)
{
    const int bid = blockIdx.x;
    const float* src; _Float16* dst; size_t off;
    if (bid < 4096) {
        src = x; dst = x_h; off = (size_t)bid * 2048;
    } else {
        const int b2 = bid - 4096;
        const int w = b2 >> 9;
        src = (w == 0) ? Wq : ((w == 1) ? Wk : Wv);
        dst = Wh + (size_t)w * 1048576;
        off = (size_t)(b2 & 511) * 2048;
    }
    const size_t i = off + (size_t)threadIdx.x * 8;
    float4 a = *(const float4*)(src + i);
    float4 b = *(const float4*)(src + i + 4);
    h8 o = { (_Float16)a.x, (_Float16)a.y, (_Float16)a.z, (_Float16)a.w,
             (_Float16)b.x, (_Float16)b.y, (_Float16)b.z, (_Float16)b.w };
    *(h8*)(dst + i) = o;
}

// causal row stats: per row compute {max, 1/sum} (reduction order bitwise
// identical to the old softmax kernel). Thread t owns cols 8t..8t+7.
__global__ __launch_bounds__(256) void rowstat(const float* __restrict__ S,
                                               float2* __restrict__ MS)
{
    const int idx = blockIdx.x;          // 0..8191
    const int q = idx & 2047;
    const float* Srow = S + (size_t)idx * 2048;
    const int t = threadIdx.x;
    const int k0 = t * 8;
    const int lane = t & 63, wv = t >> 6;
    __shared__ float red[4];

    float v[8];
    const bool any = (k0 <= q);
    if (any) {
        float4 a = *(const float4*)(Srow + k0);
        float4 b = *(const float4*)(Srow + k0 + 4);
        v[0] = a.x; v[1] = a.y; v[2] = a.z; v[3] = a.w;
        v[4] = b.x; v[5] = b.y; v[6] = b.z; v[7] = b.w;
    }
    float mx = -3.4e38f;
    #pragma unroll
    for (int j = 0; j < 8; j++)
        if (any && k0 + j <= q) mx = fmaxf(mx, v[j]);
    #pragma unroll
    for (int o = 32; o > 0; o >>= 1) mx = fmaxf(mx, __shfl_down(mx, o, 64));
    if (lane == 0) red[wv] = mx;
    __syncthreads();
    const float mall = fmaxf(fmaxf(red[0], red[1]), fmaxf(red[2], red[3]));
    __syncthreads();

    float sum = 0.f;
    #pragma unroll
    for (int j = 0; j < 8; j++) {
        float e = (any && k0 + j <= q) ? __expf(v[j] - mall) : 0.f;
        sum += e;
    }
    #pragma unroll
    for (int o = 32; o > 0; o >>= 1) sum += __shfl_down(sum, o, 64);
    if (lane == 0) red[wv] = sum;
    __syncthreads();
    if (t == 0) {
        const float inv = 1.f / (red[0] + red[1] + red[2] + red[3]);
        MS[idx] = make_float2(mall, inv);
    }
}

extern "C" void kernel_launch(void* const* d_in, const int* in_sizes, int n_in,
                              void* d_out, int out_size, void* d_ws, size_t ws_size,
                              hipStream_t stream) {
    const float* x  = (const float*)d_in[0];
    const float* Wq = (const float*)d_in[1];
    const float* Wk = (const float*)d_in[2];
    const float* Wv = (const float*)d_in[3];
    float* out = (float*)d_out;

    const size_t MiB = 1024 * 1024;
    char* ws = (char*)d_ws;
    _Float16* QKVh = (_Float16*)ws;                     // Q,K slabs + Vt at slab 2
    _Float16* Vt   = QKVh + (size_t)2 * 8388608;        // [32,48) MiB, (b,e,s)
    float*    S    = (float*)(ws + 48 * MiB);           // 64 MiB
    _Float16* x_h  = (_Float16*)(ws + 48 * MiB);        // 16 MiB (over S)
    _Float16* Wh   = (_Float16*)(ws + 64 * MiB);        // 6 MiB  (over S)
    float2*   MS   = (float2*)ws;                       // 64 KB (over dead Q)

    const dim3 blk(256);

    // 0) fp32 -> fp16 conversions (one dispatch)
    cvt_all<<<dim3(5632), blk, 0, stream>>>(x, Wq, Wk, Wv, x_h, Wh);

    // 1) QKV fused, 256x192 dense-staged pipeline (R10 best): M=8192, N=3072
    qkv192<<<dim3(512), dim3(512), 0, stream>>>(x_h, Wh, QKVh);

    // 2) scores: balanced lower-triangle decode, 136 tiles/batch
    gemm_nt<2, 0, false><<<dim3(136, 1, 4), blk, 0, stream>>>(
        QKVh, QKVh + 8388608, S, 2048, 1024,
        (size_t)2097152, (size_t)2097152, (size_t)4194304);

    // 3) causal row stats {max, 1/sum} (Q,K slabs dead -> MS overlays)
    rowstat<<<dim3(4 * 2048), blk, 0, stream>>>(S, MS);

    // 4) out = softmax(S) @ Vt^T fused (pipelined), K clipped at m0+128
    pv_fused<<<dim3(128, 1, 4), blk, 0, stream>>>(S, MS, Vt, out);
}

// Round 9
// 237.147 us; speedup vs baseline: 1.3316x; 1.1660x over previous
//
#include <hip/hip_runtime.h>

// ---------------------------------------------------------------------------
// SelfAttention: B=4, S=2048, D=1024, fp32 in/out, causal, no 1/sqrt(d).
// fp16 MFMA (16x16x32), fp32 accumulate, fp32 softmax.
//
// R17 = R2's proven config (237.4 us: cvt + qkv192 + scores + softmax + PV)
// with ONE change: PV uses an LPT-paired flat decode (SWZ=4, grid 512).
// R16 exposed that grid (128,1,4) + x-major dispatch puts blocks k and
// k+256 (same by => same triangular workload) on the same CU: by=15 CUs
// serialize 2x32 K-iters while by=0 CUs idle (Occ 12%). SWZ=4 pairs heavy
// (by 15..8) with light (by 0..7) so every CU pair totals 34 K-iters.
// Pure block remap — per-block math unchanged, absmax must be 0.09765625.
// The rowstat+pv_fused experiment (R14-R16) is reverted: measured 104 us
// combined vs 63 us for the split softmax+PV.
//
// ws layout (MiB):
//   [0,32)    Q,K fp16 slabs; later P fp16 overlays (after scores read Q,K)
//   [32,48)   Vt fp16 (b,e,s) — written by QKV epilogue
//   [48,112)  S fp32 (4x2048x2048)
//   [48,64)   x_h fp16      (over S; dead before S written)
//   [64,70)   Wh  fp16 [3072,1024] (over S; dead before S written)
// ---------------------------------------------------------------------------

typedef _Float16 h8 __attribute__((ext_vector_type(8)));
typedef _Float16 h4 __attribute__((ext_vector_type(4)));
typedef float f32x4 __attribute__((ext_vector_type(4)));

#define BM 128
#define BN 128

__device__ __forceinline__ void gl_lds16(const _Float16* g, _Float16* l) {
    __builtin_amdgcn_global_load_lds(
        (const __attribute__((address_space(1))) void*)g,
        (__attribute__((address_space(3))) void*)l, 16, 0, 0);
}

#define BARX do { asm volatile("" ::: "memory"); __builtin_amdgcn_s_barrier(); \
                  asm volatile("" ::: "memory"); } while (0)
#define VMW(n) asm volatile("s_waitcnt vmcnt(" #n ")" ::: "memory")

// ---------------------------------------------------------------------------
// qkv192 (R10 verbatim): A = x_h [8192][1024], B = Wh [3072][1024].
// 8 waves 2Mx4N, per-wave 128x48 (8 M-frags x 3 N-frags), acc[8][3].
// LDS: Ab0@0 Ab1@16384 Ab2@32768 ([256][64]); Bb0@49152 Bb1@61440
// ([192][64]) = 144 KiB. Dense 128B-line staging, XOR seg swizzle on the
// global source. 4 phases/window, vmcnt(4) once per window.
// ---------------------------------------------------------------------------

#define SA_LO(gp, ab) do { gl_lds16((gp),          (ab) + wv * 1024); \
                           gl_lds16((gp) + 8192,   (ab) + wv * 1024 + 512); } while (0)
#define SA_HI(gp, ab) do { gl_lds16((gp) + 131072, (ab) + wv * 1024 + 8192); \
                           gl_lds16((gp) + 139264, (ab) + wv * 1024 + 8704); } while (0)
#define SB_LO(gp, bb) do { gl_lds16((gp),          (bb) + wv * 1024); \
                           gl_lds16((gp) + 8192,   (bb) + wv * 1024 + 512); } while (0)
#define SB_HI(gp2, bb)     gl_lds16((gp2),         (bb) + 8192 + wv * 512)

#define LDA(ab, h, ap) do { _Pragma("unroll") \
    for (int i = 0; i < 4; i++) \
        af[i] = *(const h8*)&(ab)[abase + (h) * 4096 + i * 1024 + (ap)]; } while (0)
#define LDB(bb, ap) do { _Pragma("unroll") \
    for (int j = 0; j < 3; j++) \
        bf[j] = *(const h8*)&(bb)[bbase + j * 1024 + (ap)]; } while (0)

#define MMP(h) do { __builtin_amdgcn_s_setprio(1); _Pragma("unroll") \
    for (int i = 0; i < 4; i++) { _Pragma("unroll") \
        for (int j = 0; j < 3; j++) \
            acc[(h) * 4 + i][j] = __builtin_amdgcn_mfma_f32_16x16x32_f16( \
                af[i], bf[j], acc[(h) * 4 + i][j], 0, 0, 0); } \
    __builtin_amdgcn_s_setprio(0); } while (0)

__global__ __launch_bounds__(512, 2) void qkv192(
    const _Float16* __restrict__ A, const _Float16* __restrict__ B,
    _Float16* __restrict__ C)
{
    __shared__ __align__(16) _Float16 sm[73728];   // 144 KiB

    // XCD-bijective swizzle (512 % 8 == 0)
    const int bid = blockIdx.x;
    const int wg = (bid & 7) * 64 + (bid >> 3);
    const int by = wg >> 4, bx = wg & 15;
    const int m0 = by * 256, n0 = bx * 192;

    const int tid = threadIdx.x;
    const int l = tid & 63;
    const int wv = tid >> 6;

    // staging addressing: lane l -> row +(l>>3), global seg (l&7)^((l>>3)&7)
    const int prow = wv * 16 + (l >> 3);
    const int pseg = ((l & 7) ^ ((l >> 3) & 7)) * 8;
    const _Float16* gA  = A + (size_t)(m0 + prow) * 1024 + pseg;
    const _Float16* gB  = B + (size_t)(n0 + prow) * 1024 + pseg;
    const _Float16* gB2 = B + (size_t)(n0 + 128 + wv * 8 + (l >> 3)) * 1024 + pseg;

    // fragment addressing
    const int la = l & 15, qd = l >> 4;
    const int wmr = (wv >> 2) * 128;            // 2 M row-groups
    const int wnr = (wv & 3) * 48;              // 4 N col-groups of 48
    const int ap0 = ((qd) ^ (la & 7)) * 8;      // k-step s=0 phys seg
    const int ap1 = ((4 + qd) ^ (la & 7)) * 8;  // k-step s=1 phys seg
    const int abase = (wmr + la) * 64;
    const int bbase = (wnr + la) * 64;

    _Float16* a0 = sm;
    _Float16* a1 = sm + 16384;
    _Float16* a2 = sm + 32768;
    _Float16* b0 = sm + 49152;
    _Float16* b1 = sm + 61440;

    f32x4 acc[8][3];
    #pragma unroll
    for (int i = 0; i < 8; i++)
        #pragma unroll
        for (int j = 0; j < 3; j++)
            acc[i][j] = (f32x4){0.f, 0.f, 0.f, 0.f};

    // prologue: A(0)->Ab0, B(0)->Bb0, A(1)->Ab1 (11 ops); force A(0)+B(0)
    SA_LO(gA, a0);      SA_HI(gA, a0);
    SB_LO(gB, b0);      SB_HI(gB2, b0);
    SA_LO(gA + 64, a1); SA_HI(gA + 64, a1);
    VMW(4);
    BARX;

    const _Float16* pA  = gA + 128;    // k-offset of A(2)
    const _Float16* pB  = gB + 64;     // k-offset of B(1)
    const _Float16* pB2 = gB2 + 64;

    #pragma unroll 1
    for (int n = 0; n < 14; ++n) {
        h8 af[4], bf[3];
        LDB(b0, ap0); LDA(a0, 0, ap0); SB_LO(pB, b1);  BARX; MMP(0); BARX;
        LDA(a0, 1, ap0);               SB_HI(pB2, b1); BARX; MMP(1); BARX;
        LDB(b0, ap1); LDA(a0, 0, ap1); SA_LO(pA, a2);  BARX; MMP(0); BARX;
        LDA(a0, 1, ap1);               SA_HI(pA, a2);  BARX; MMP(1); VMW(4); BARX;
        _Float16* t = a0; a0 = a1; a1 = a2; a2 = t;
        t = b0; b0 = b1; b1 = t;
        pA += 64; pB += 64; pB2 += 64;
    }
    {   // W14: stage only B(15); drain everything at end
        h8 af[4], bf[3];
        LDB(b0, ap0); LDA(a0, 0, ap0); SB_LO(pB, b1);  BARX; MMP(0); BARX;
        LDA(a0, 1, ap0);               SB_HI(pB2, b1); BARX; MMP(1); BARX;
        LDB(b0, ap1); LDA(a0, 0, ap1);                 BARX; MMP(0); BARX;
        LDA(a0, 1, ap1);                               BARX; MMP(1); VMW(0); BARX;
        _Float16* t = a0; a0 = a1; a1 = a2; a2 = t;
        t = b0; b0 = b1; b1 = t;
    }
    {   // W15: reads only
        h8 af[4], bf[3];
        LDB(b0, ap0); LDA(a0, 0, ap0); BARX; MMP(0); BARX;
        LDA(a0, 1, ap0);               BARX; MMP(1); BARX;
        LDB(b0, ap1); LDA(a0, 0, ap1); BARX; MMP(0); BARX;
        LDA(a0, 1, ap1);               BARX; MMP(1);
    }

    // epilogue: D layout col=la, row=qd*4+rr. Slab per 16-aligned column.
    #pragma unroll
    for (int i = 0; i < 8; i++) {
        const int m = m0 + wmr + i * 16 + qd * 4;
        #pragma unroll
        for (int j = 0; j < 3; j++) {
            const int col16 = n0 + wnr + j * 16;
            const int slab = col16 >> 10;
            if (slab < 2) {
                const size_t base = (size_t)slab * 8388608 + (col16 & 1023) + la;
                #pragma unroll
                for (int rr = 0; rr < 4; rr++)
                    C[base + (size_t)(m + rr) * 1024] = (_Float16)acc[i][j][rr];
            } else {
                _Float16* Vt = C + (size_t)2 * 8388608;
                const int e = col16 + la - 2048;
                const int b = m >> 11;
                const int sl = m & 2047;
                h4 vv = { (_Float16)acc[i][j][0], (_Float16)acc[i][j][1],
                          (_Float16)acc[i][j][2], (_Float16)acc[i][j][3] };
                *(h4*)(Vt + (size_t)b * 2097152 + (size_t)e * 2048 + sl) = vv;
            }
        }
    }
}

// ---------------------------------------------------------------------------
// NT GEMM: SWZ 2 = scores balanced triangle (grid 136, z=batch);
//          SWZ 4 = PV LPT-paired flat decode (grid 512, z folded in).
// ---------------------------------------------------------------------------
template<int SWZ, int OM, bool KLIM>
__global__ __launch_bounds__(256) void gemm_nt(
    const _Float16* __restrict__ A, const _Float16* __restrict__ B,
    void* __restrict__ Cp, int N, int K,
    size_t sAz, size_t sBz, size_t sCz)
{
    __shared__ __align__(16) char smem[32768];
    _Float16* As = (_Float16*)smem;              // 2 x 4096 halves (k-stages)
    _Float16* Bs = (_Float16*)(smem + 16384);    // 2 x 4096 halves

    int bx, by, zz = (int)blockIdx.z;
    if (SWZ == 1) {
        const int r = blockIdx.x & 7, q2 = blockIdx.x >> 3;
        bx = q2 >> 3;
        by = ((q2 & 7) << 3) | r;
    } else if (SWZ == 2) {
        const int r = blockIdx.x & 7, g = blockIdx.x >> 3;   // g in 0..16
        if (g <= r) { by = r;      bx = g; }
        else        { by = 15 - r; bx = g - (r + 1); }
    } else if (SWZ == 3) {
        const int r = blockIdx.x & 7, g = blockIdx.x >> 3;   // g in 0..15
        by = (g & 1) ? (15 - r) : r;
        bx = g >> 1;
    } else {
        // SWZ == 4: LPT-paired flat decode, grid.x = 512 (PV).
        // bid<256: by 15..8 (heavy); bid>=256: by 0..7 (light). With
        // x-major dispatch CU k gets bids k and k+256: iters sum = 34
        // for every pair (uniform makespan; fixes the same-by stacking).
        const int h = blockIdx.x >> 8;
        const int j = blockIdx.x & 255;
        zz = j & 3;
        bx = (j >> 2) & 7;
        const int t = j >> 5;                    // 0..7
        by = h ? t : (15 - t);
    }

    const int tid  = threadIdx.x;
    const int lane = tid & 63;
    const int wv   = tid >> 6;
    const int m0 = by * BM, n0 = bx * BN;
    const size_t z = (size_t)zz;

    const int lr = lane >> 2;
    const int lc = ((lane & 3) ^ ((lane >> 3) & 3)) * 8;
    const _Float16* pA0 = A + z * sAz + (size_t)(m0 + wv * 16 + lr) * K + lc;
    const _Float16* pA1 = pA0 + (size_t)64 * K;
    const _Float16* pB0 = B + z * sBz + (size_t)(n0 + wv * 16 + lr) * K + lc;
    const _Float16* pB1 = pB0 + (size_t)64 * K;
    _Float16* lA0 = As + wv * 512;
    _Float16* lA1 = As + (wv + 4) * 512;
    _Float16* lB0 = Bs + wv * 512;
    _Float16* lB1 = Bs + (wv + 4) * 512;

    const int la = lane & 15;
    const int qd = lane >> 4;
    const int wm = (wv >> 1) * 64;
    const int wn = (wv & 1) * 64;
    const int sg = (qd ^ ((la >> 1) & 3)) * 8;

    f32x4 acc[4][4];
    #pragma unroll
    for (int i = 0; i < 4; i++)
        #pragma unroll
        for (int j = 0; j < 4; j++)
            acc[i][j] = (f32x4){0.f, 0.f, 0.f, 0.f};

    const int kEnd = KLIM ? (m0 + BM) : K;

    for (int k0 = 0; k0 < kEnd; k0 += 64) {
        gl_lds16(pA0,      lA0);
        gl_lds16(pA1,      lA1);
        gl_lds16(pB0,      lB0);
        gl_lds16(pB1,      lB1);
        gl_lds16(pA0 + 32, lA0 + 4096);
        gl_lds16(pA1 + 32, lA1 + 4096);
        gl_lds16(pB0 + 32, lB0 + 4096);
        gl_lds16(pB1 + 32, lB1 + 4096);
        pA0 += 64; pA1 += 64; pB0 += 64; pB1 += 64;
        __syncthreads();

        #pragma unroll
        for (int s = 0; s < 2; s++) {
            h8 af[4], bf[4];
            #pragma unroll
            for (int i = 0; i < 4; i++)
                af[i] = *(const h8*)&As[s * 4096 + (wm + i * 16 + la) * 32 + sg];
            #pragma unroll
            for (int i = 0; i < 4; i++)
                bf[i] = *(const h8*)&Bs[s * 4096 + (wn + i * 16 + la) * 32 + sg];
            #pragma unroll
            for (int i = 0; i < 4; i++)
                #pragma unroll
                for (int j = 0; j < 4; j++)
                    acc[i][j] = __builtin_amdgcn_mfma_f32_16x16x32_f16(af[i], bf[j], acc[i][j], 0, 0, 0);
        }
        __syncthreads();
    }

    if (OM == 2) {
        _Float16* C = (_Float16*)Cp;
        if (n0 < 2048) {
            #pragma unroll
            for (int i = 0; i < 4; i++)
                #pragma unroll
                for (int j = 0; j < 4; j++) {
                    const int col  = n0 + wn + j * 16 + la;
                    const size_t base = (size_t)(col >> 10) * 8388608 + (col & 1023);
                    #pragma unroll
                    for (int rr = 0; rr < 4; rr++)
                        C[base + (size_t)(m0 + wm + i * 16 + qd * 4 + rr) * 1024] =
                            (_Float16)acc[i][j][rr];
                }
        } else {
            _Float16* Vt = C + (size_t)2 * 8388608;
            #pragma unroll
            for (int i = 0; i < 4; i++) {
                const int m  = m0 + wm + i * 16 + qd * 4;
                const int b  = m >> 11;
                const int sl = m & 2047;
                _Float16* Vb = Vt + (size_t)b * 2097152 + sl;
                #pragma unroll
                for (int j = 0; j < 4; j++) {
                    const int e = n0 - 2048 + wn + j * 16 + la;
                    h4 vv = { (_Float16)acc[i][j][0], (_Float16)acc[i][j][1],
                              (_Float16)acc[i][j][2], (_Float16)acc[i][j][3] };
                    *(h4*)(Vb + (size_t)e * 2048) = vv;
                }
            }
        }
    } else {
        float* C = (float*)Cp + z * sCz;
        #pragma unroll
        for (int i = 0; i < 4; i++)
            #pragma unroll
            for (int j = 0; j < 4; j++)
                #pragma unroll
                for (int rr = 0; rr < 4; rr++)
                    C[(size_t)(m0 + wm + i * 16 + qd * 4 + rr) * N + (n0 + wn + j * 16 + la)] =
                        acc[i][j][rr];
    }
}

// fused fp32->fp16: blocks [0,4096) convert x (8M), [4096,5632) convert W (3x1M)
__global__ __launch_bounds__(256) void cvt_all(
    const float* __restrict__ x, const float* __restrict__ Wq,
    const float* __restrict__ Wk, const float* __restrict__ Wv,
    _Float16* __restrict__ x_h, _Float16* __restrict__ Wh)
{
    const int bid = blockIdx.x;
    const float* src; _Float16* dst; size_t off;
    if (bid < 4096) {
        src = x; dst = x_h; off = (size_t)bid * 2048;
    } else {
        const int b2 = bid - 4096;
        const int w = b2 >> 9;
        src = (w == 0) ? Wq : ((w == 1) ? Wk : Wv);
        dst = Wh + (size_t)w * 1048576;
        off = (size_t)(b2 & 511) * 2048;
    }
    const size_t i = off + (size_t)threadIdx.x * 8;
    float4 a = *(const float4*)(src + i);
    float4 b = *(const float4*)(src + i + 4);
    h8 o = { (_Float16)a.x, (_Float16)a.y, (_Float16)a.z, (_Float16)a.w,
             (_Float16)b.x, (_Float16)b.y, (_Float16)b.z, (_Float16)b.w };
    *(h8*)(dst + i) = o;
}

// causal row softmax: S fp32 -> P fp16. Thread t owns cols 8t..8t+7.
// Reads only k<=q; writes only k < 128*ceil((q+1)/128) (PV never reads more).
__global__ __launch_bounds__(256) void softmax_causal(const float* __restrict__ S,
                                                      _Float16* __restrict__ P)
{
    const int idx = blockIdx.x;          // 0..8191
    const int q = idx & 2047;
    const float* Srow = S + (size_t)idx * 2048;
    _Float16* Prow = P + (size_t)idx * 2048;
    const int t = threadIdx.x;
    const int k0 = t * 8;
    const int lane = t & 63, wv = t >> 6;
    __shared__ float red[4];

    float v[8];
    const bool any = (k0 <= q);
    if (any) {
        float4 a = *(const float4*)(Srow + k0);
        float4 b = *(const float4*)(Srow + k0 + 4);
        v[0] = a.x; v[1] = a.y; v[2] = a.z; v[3] = a.w;
        v[4] = b.x; v[5] = b.y; v[6] = b.z; v[7] = b.w;
    }
    float mx = -3.4e38f;
    #pragma unroll
    for (int j = 0; j < 8; j++)
        if (any && k0 + j <= q) mx = fmaxf(mx, v[j]);
    #pragma unroll
    for (int o = 32; o > 0; o >>= 1) mx = fmaxf(mx, __shfl_down(mx, o, 64));
    if (lane == 0) red[wv] = mx;
    __syncthreads();
    const float mall = fmaxf(fmaxf(red[0], red[1]), fmaxf(red[2], red[3]));
    __syncthreads();

    float sum = 0.f;
    #pragma unroll
    for (int j = 0; j < 8; j++) {
        float e = (any && k0 + j <= q) ? __expf(v[j] - mall) : 0.f;
        v[j] = e;
        sum += e;
    }
    #pragma unroll
    for (int o = 32; o > 0; o >>= 1) sum += __shfl_down(sum, o, 64);
    if (lane == 0) red[wv] = sum;
    __syncthreads();
    const float inv = 1.f / (red[0] + red[1] + red[2] + red[3]);

    const int kceil = ((q >> 7) + 1) << 7;       // PV reads cols < kceil
    if (k0 < kceil) {
        h8 o = { (_Float16)(v[0] * inv), (_Float16)(v[1] * inv),
                 (_Float16)(v[2] * inv), (_Float16)(v[3] * inv),
                 (_Float16)(v[4] * inv), (_Float16)(v[5] * inv),
                 (_Float16)(v[6] * inv), (_Float16)(v[7] * inv) };
        *(h8*)(Prow + k0) = o;
    }
}

extern "C" void kernel_launch(void* const* d_in, const int* in_sizes, int n_in,
                              void* d_out, int out_size, void* d_ws, size_t ws_size,
                              hipStream_t stream) {
    const float* x  = (const float*)d_in[0];
    const float* Wq = (const float*)d_in[1];
    const float* Wk = (const float*)d_in[2];
    const float* Wv = (const float*)d_in[3];
    float* out = (float*)d_out;

    const size_t MiB = 1024 * 1024;
    char* ws = (char*)d_ws;
    _Float16* QKVh = (_Float16*)ws;                     // Q,K slabs + Vt at slab 2
    _Float16* Vt   = QKVh + (size_t)2 * 8388608;        // [32,48) MiB, (b,e,s)
    float*    S    = (float*)(ws + 48 * MiB);           // 64 MiB
    _Float16* x_h  = (_Float16*)(ws + 48 * MiB);        // 16 MiB (over S)
    _Float16* Wh   = (_Float16*)(ws + 64 * MiB);        // 6 MiB  (over S)
    _Float16* P    = (_Float16*)ws;                     // 32 MiB (over Q,K)

    const dim3 blk(256);

    // 0) fp32 -> fp16 conversions (one dispatch)
    cvt_all<<<dim3(5632), blk, 0, stream>>>(x, Wq, Wk, Wv, x_h, Wh);

    // 1) QKV fused, 256x192 dense-staged pipeline (R10 best): M=8192, N=3072
    qkv192<<<dim3(512), dim3(512), 0, stream>>>(x_h, Wh, QKVh);

    // 2) scores: balanced lower-triangle decode, 136 tiles/batch
    gemm_nt<2, 0, false><<<dim3(136, 1, 4), blk, 0, stream>>>(
        QKVh, QKVh + 8388608, S, 2048, 1024,
        (size_t)2097152, (size_t)2097152, (size_t)4194304);

    // 3) causal softmax rows -> P fp16 (over Q,K)
    softmax_causal<<<dim3(4 * 2048), blk, 0, stream>>>(S, P);

    // 4) out = P @ Vt^T, fp32 out, K clipped at m0+128, LPT-paired decode
    gemm_nt<4, 0, true><<<dim3(512), blk, 0, stream>>>(
        P, Vt, out, 1024, 2048,
        (size_t)4194304, (size_t)2097152, (size_t)2097152);
}